// Round 6
// baseline (359.978 us; speedup 1.0000x reference)
//
#include <hip/hip_runtime.h>
#include <cfloat>
#include <math.h>

#define NROW   256      // B*E rows
#define RLEN   65536    // N*N elements per row
#define TPB    1024
#define VPT    64       // register-resident values per thread (64*1024 = RLEN)
#define REGS   8        // candidate slots per thread
#define MAXC   (TPB*REGS)   // 8192
#define NITER  64       // scan length (local_k)
#define KSEL   64       // top-k
#define THETA_OFF 8.0f  // initial candidate threshold: M0 - 8.0
#define TCAP   256      // tie-list capacity
#define LN_TGT 7.6246f  // ln(2048): adaptive-theta target count
#define WGATE_D 1.4787e-8   // e^-18.03: suppression gate (o > this)

// R14 = R13's w-space scan with the state lifted to f64 — fixes R13's failure:
// ROOT CAUSE of R13 absmax=1.0: fp32 w = exp(10(v-M0)) UNDERFLOWS TO 0 on
// rows where adaptive theta stepped below ~M0-8.8 (count(M0-8) < 64, ~2% of
// rows: large top-gap). Those candidates' khot froze at 0, but in the
// reference they gain O(1) khot in later iterations once Lse drops ->
// wrong selected set on ~5 rows/launch. f64 range (e^+-700) eliminates the
// mechanism for any reachable theta; f64 precision (1e-16) also removes
// R13's decorrelated ranking drift vs the reference trajectory.
// Structure kept from R13: zero-transcendental scan (o = w*rcpS;
// w *= (1-o)^10 via 4 muls; S = sum(w)+U pure adds), ONE barrier/iter,
// S < Ktrig expansion trigger, Rsum backfill. New in R14:
//  - khot accumulates in f64 REGISTERS kh[8] (deletes the per-iteration
//    gated LDS RMW on cand_kv; single (float)kh store after the scan);
//  - accumulation is UNGATED (kh += w*rcpS every iter — closer to the
//    reference; the e^-18.03 gate now only skips the suppression update,
//    same semantics as R12's flat-update gate);
//  - one-time conversion + expansion backfill use f64 exp().
// Collect, adaptive theta, expansion re-scan (f32 values, bit-identical),
// radix top-64, tie-break emit: R12-verbatim (the passing lineage).
// LDS ~81.5 KB keeps 1 block/CU.
__global__ void __launch_bounds__(TPB, 4)
GumbelSampler_2482491097709_kernel(const float* __restrict__ scores,
                                   const float* __restrict__ gumbel,
                                   float* __restrict__ out)
{
    __shared__ double s_Pd[2][16];  // scan sum partials (ping-pong, f64)
    __shared__ float s_EA[16];      // collect/expansion max partials
    __shared__ float s_EB[16];      // collect/expansion sum partials
    __shared__ int   s_IC[16];      // adaptive-theta count partials
    __shared__ int   s_cnt;
    __shared__ int   s_selB;        // histogram: found bin (per pass)
    __shared__ int   s_selR;        // histogram: residual rank (per pass)
    __shared__ int   s_tcnt;
    __shared__ int   s_tie[TCAP];
    __shared__ int   s_hist[4096];  // 16 KB: radix passes use <=2048 bins;
                                    // oversized on purpose (LDS > 80 KB)
    __shared__ int   cand_idx[MAXC];
    __shared__ float cand_kv[MAXC]; // staging value, then final (float)khot

    const int tid  = threadIdx.x;
    const int lane = tid & 63;
    const int wid  = tid >> 6;

    // XCD swizzle: co-locate the 4 e-blocks of each b on one XCD (perf only).
    const int q    = blockIdx.x;
    const int xcd  = q & 7;
    const int slot = q >> 3;
    const int b    = xcd * 8 + (slot & 7);
    const int e    = slot >> 3;
    const int r    = b * 4 + e;

    const float* __restrict__ sr = scores + (size_t)b * (RLEN * 4) + e;
    const float* __restrict__ gr = gumbel + (size_t)r * RLEN;

    // ---- Single global read: v[s] for positions p = tid + TPB*s; fused max ----
    float v[VPT];
    float lm = -FLT_MAX;
#pragma unroll
    for (int s = 0; s < VPT; ++s) {
        int p = tid + TPB * s;
        float x = sr[(size_t)p * 4] + gr[p];
        v[s] = x;
        lm = fmaxf(lm, x);
    }
    // Pin v[] into registers: forbids rematerialization-from-global.
#pragma unroll
    for (int s = 0; s < VPT; ++s) asm volatile("" : "+v"(v[s]));

    // ---- Block max M0 (exact; uniform via commutative fmax butterfly) ----
#pragma unroll
    for (int o = 32; o; o >>= 1) lm = fmaxf(lm, __shfl_xor(lm, o));
    if (lane == 0) s_EA[wid] = lm;
    __syncthreads();
    float M0 = s_EA[lane & 15];
#pragma unroll
    for (int o = 8; o; o >>= 1) M0 = fmaxf(M0, __shfl_xor(M0, o));
    const float  C  = M0 * 10.0f;        // f32 anchor (tail-U arithmetic)
    const double M0d = (double)M0;       // f64 anchor base for w

    // ---- Adaptive theta: exact count from registers, ln-step to ~2048 ----
    // count predicate (v[s] >= theta) is IDENTICAL to the append predicate,
    // so the final cnt equals the accepted count exactly: no overflow path.
    float theta = M0 - THETA_OFF;
    for (int probe = 0; probe < 12; ++probe) {
        int lc = 0;
#pragma unroll
        for (int s = 0; s < VPT; ++s) lc += (v[s] >= theta) ? 1 : 0;
#pragma unroll
        for (int o = 32; o; o >>= 1) lc += __shfl_xor(lc, o);
        if (lane == 0) s_IC[wid] = lc;
        __syncthreads();
        int cc = s_IC[lane & 15];
#pragma unroll
        for (int o = 8; o; o >>= 1) cc += __shfl_xor(cc, o);   // uniform
        __syncthreads();                 // s_IC reads done before next write
        if (cc > MAXC - 64)      theta += __logf((float)cc) - LN_TGT;  // up
        else if (cc < KSEL)      theta -= LN_TGT - __logf((float)(cc < 1 ? 1 : cc));
        else break;                      // 64 <= cnt <= 8128: accept
    }

    // ---- Collect candidates + frozen-tail Mu/U (from registers, f32) ----
    // Warp-aggregated append: one LDS atomic per wave-iteration.
    if (tid == 0) s_cnt = 0;
    __syncthreads();
    {
        float mu = -FLT_MAX, u = 0.f;
#pragma unroll
        for (int s = 0; s < VPT; ++s) {
            float val = v[s];
            bool pr = (val >= theta);
            unsigned long long m = __ballot(pr);
            if (pr) {
                int lead = __ffsll(m) - 1;
                int base = 0;
                if (lane == lead) base = atomicAdd(&s_cnt, (int)__popcll(m));
                base = __shfl(base, lead);
                int sl = base + (int)__popcll(m & ((1ull << lane) - 1ull));
                if (sl < MAXC) { cand_idx[sl] = tid + TPB * s; cand_kv[sl] = val; }
            } else {
                mu = fmaxf(mu, val);
                float yv = fmaf(val, 10.f, -C);
                if (yv > -87.f) u += __expf(yv);   // below -87 flushes anyway
            }
        }
#pragma unroll
        for (int o = 32; o; o >>= 1) {
            mu = fmaxf(mu, __shfl_xor(mu, o));
            u += __shfl_xor(u, o);
        }
        if (lane == 0) { s_EA[wid] = mu; s_EB[wid] = u; }
    }
    __syncthreads();                     // staging + partials visible
    int cnt = s_cnt;
    float Mu = s_EA[lane & 15], Uf = s_EB[lane & 15];
#pragma unroll
    for (int o = 8; o; o >>= 1) {
        Mu = fmaxf(Mu, __shfl_xor(Mu, o));
        Uf += __shfl_xor(Uf, o);
    }
    double Ud = (double)Uf;
    // v[] is dead past this point; the rare expansion path re-reads global
    // with identical arithmetic.

    // ---- Owner pull: w = exp(10(v - M0)) in f64 -> registers; kh = 0 ----
    double w[REGS], kh[REGS];
#pragma unroll
    for (int j = 0; j < REGS; ++j) {
        int sl = tid + TPB * j;
        if (sl < cnt) w[j] = exp(10.0 * ((double)cand_kv[sl] - M0d));
        else          w[j] = 0.0;
        kh[j] = 0.0;
    }

    // ---- f64 w-space scan: 64 iterations, ONE barrier, NO transcendentals ----
    // Iteration t: accumulate onehot_{t-1} (o = w*rcpS, ungated), suppress
    // w *= (1-o)^10 when o > e^-18.03, sum S_t = sum(w) + U.
    bool   noexp = false;
    double rcpS = 0.0, wT = 1e300;       // t=0: nothing suppressed
    double Rsum = 0.0;                   // sum_{tt<t} rcpS_tt (for backfill)
    double Ktrig = exp(fma(10.0, (double)Mu, -10.0 * M0d + 20.0));
    for (int t = 0; t < NITER; ++t) {
        const int pb = t & 1;
        double ls = 0.0;
#pragma unroll
        for (int j = 0; j < REGS; ++j) {
            int sl = tid + TPB * j;
            if (sl < cnt) {
                double wj = w[j];
                double o  = wj * rcpS;   // onehot_{t-1} (0 at t=0)
                kh[j] += o;              // UNGATED accumulate (reference-true)
                if (wj > wT) {           // suppression gate: o > e^-18.03
                    double m  = 1.0 - o;
                    double m2 = m * m;
                    double m4 = m2 * m2;
                    double m8 = m4 * m4;
                    wj *= m8 * m2;       // w *= (1-o)^10
                    w[j] = wj;
                }
                ls += wj;
            }
        }
#pragma unroll
        for (int o = 32; o; o >>= 1) ls += __shfl_xor(ls, o);
        if (lane == 0) s_Pd[pb][wid] = ls;
        __syncthreads();                 // THE one barrier of this iteration
        double S = s_Pd[pb][lane & 15];  // same-address bcast per 16-lane group
#pragma unroll
        for (int o = 8; o; o >>= 1) S += __shfl_xor(S, o);   // uniform
        S += Ud;                         // frozen tail: direct add at anchor
        rcpS = 1.0 / S;
        wT   = S * WGATE_D;

        // Expansion trigger (uniform): S < Ktrig <=> 10*Mu > Lse - 20.
        if (!noexp && t < NITER - 1 && S < Ktrig) {
            double Lse  = fma(10.0, M0d, log(S));
            float thOld = theta;
            float thN   = (float)((Lse - 26.0) * 0.1);
            int   oldc  = cnt;
            float mu2 = -FLT_MAX, u2 = 0.f;
#pragma unroll 4
            for (int s = 0; s < VPT; ++s) {
                int p = tid + TPB * s;
                float val = sr[(size_t)p * 4] + gr[p];   // bit-identical v
                if (val < thOld) {
                    if (val >= thN) {
                        int sl = atomicAdd(&s_cnt, 1);
                        if (sl < MAXC) {
                            cand_idx[sl] = p;
                            cand_kv[sl]  = val;   // staged, bit-frozen
                        }
                    } else {
                        mu2 = fmaxf(mu2, val);
                        float yv = fmaf(val, 10.f, -C);
                        if (yv > -87.f) u2 += __expf(yv);
                    }
                }
            }
#pragma unroll
            for (int o = 32; o; o >>= 1) {
                mu2 = fmaxf(mu2, __shfl_xor(mu2, o));
                u2 += __shfl_xor(u2, o);
            }
            if (lane == 0) { s_EA[wid] = mu2; s_EB[wid] = u2; }
            __syncthreads();             // appends + partials visible
            int newc = s_cnt;
            if (newc > MAXC) {
                if (tid == 0) s_cnt = oldc;  // discard partial appends
                noexp = true;                // uniform; never expand again
            } else {
                float m2_ = s_EA[lane & 15], uu = s_EB[lane & 15];
#pragma unroll
                for (int o = 8; o; o >>= 1) {
                    m2_ = fmaxf(m2_, __shfl_xor(m2_, o));
                    uu += __shfl_xor(uu, o);
                }
                Mu = m2_; Ud = (double)uu; theta = thN;
                Ktrig = exp(fma(10.0, (double)Mu, -10.0 * M0d + 20.0));
                // owners pull new slots: w in f64; khot backfill = w * Rsum
                // (= sum_{tt<t} onehot_tt, each term < e^-26).
#pragma unroll
                for (int j = 0; j < REGS; ++j) {
                    int sl = tid + TPB * j;
                    if (sl >= oldc && sl < newc) {
                        double wn = exp(10.0 * ((double)cand_kv[sl] - M0d));
                        w[j]  = wn;
                        kh[j] = wn * Rsum;
                    }
                }
                cnt = newc;
            }
        }
        Rsum += rcpS;                    // now includes rcpS_t (for t+1 joins)
    }
    // final iteration's onehot (t = NITER-1) + store khot to LDS as f32
#pragma unroll
    for (int j = 0; j < REGS; ++j) {
        int sl = tid + TPB * j;
        if (sl < cnt) {
            kh[j] += w[j] * rcpS;
            cand_kv[sl] = (float)kh[j];
        }
    }
    __syncthreads();       // all khot final & visible to all threads

    // ---- Radix-histogram top-64 (exact, jax top_k tie-break) ----
    // Keys = __float_as_uint(khot), khot >= 0 -> bit order == value order.
    // kh == 0 slots are excluded (>=64 positive khot guaranteed: the true
    // top-64 each have khot >= 1.5e-5, far above fp32-zero).
    // Pass bins: [31:21] (2048), [20:10] (2048), [9:0] (1024). After each
    // pass, wave 0 finds the bin holding descending-rank Rrem and the
    // residual rank within it. After pass 3: K* = exact 64th-largest key,
    // Rrem = number of ties (== K*) to take, smallest index first.
    unsigned prefix = 0;
    int Rrem = KSEL;
    for (int pass = 0; pass < 3; ++pass) {
        const int nbins = (pass == 2) ? 1024 : 2048;
        for (int i = tid; i < nbins; i += TPB) s_hist[i] = 0;
        __syncthreads();
#pragma unroll
        for (int j = 0; j < REGS; ++j) {
            int sl = tid + TPB * j;
            if (sl < cnt) {
                unsigned key = __float_as_uint(cand_kv[sl]);
                if (key != 0u) {
                    bool m; int bin;
                    if (pass == 0)      { m = true;                     bin = key >> 21; }
                    else if (pass == 1) { m = (key >> 21) == prefix;    bin = (key >> 10) & 2047; }
                    else                { m = (key >> 10) == prefix;    bin = key & 1023; }
                    if (m) atomicAdd(&s_hist[bin], 1);
                }
            }
        }
        __syncthreads();
        if (wid == 0) {
            int Rl = Rrem, found = -1;
            const int nch = nbins >> 6;
            // pass 0: khot <= 64(1+eps) => key < bits(80.f) => bins >= 576
            // empty; skip chunks 0..22 (bins 2047..576) of the serial scan.
            const int c0 = (pass == 0) ? 23 : 0;
            for (int c = c0; c < nch && found < 0; ++c) {
                int bin = nbins - 1 - (c * 64 + lane);   // descending bins
                int h = s_hist[bin];
                int cum = h;
#pragma unroll
                for (int s2 = 1; s2 < 64; s2 <<= 1) {
                    int vv = __shfl_up(cum, s2);
                    if (lane >= s2) cum += vv;
                }
                unsigned long long mb = __ballot(cum >= Rl);
                if (mb) {
                    int fl = __ffsll(mb) - 1;            // first (highest) bin
                    int cumex = __shfl(cum, fl) - __shfl(h, fl);
                    found = nbins - 1 - (c * 64 + fl);
                    Rl -= cumex;                          // rank inside bin
                } else {
                    Rl -= __shfl(cum, 63);                // whole chunk above
                }
            }
            if (lane == 0) { s_selB = found; s_selR = Rl; }
        }
        __syncthreads();
        prefix = (prefix << ((pass == 2) ? 10 : 11)) | (unsigned)s_selB;
        Rrem = s_selR;
    }
    const unsigned Kstar = prefix;       // exact 64th-largest key
    const int need = Rrem;               // ties to take (>= 1)

    // ---- Emit: all key > K*; collect ties == K* ----
    if (tid == 0) s_tcnt = 0;
    __syncthreads();
#pragma unroll
    for (int j = 0; j < REGS; ++j) {
        int sl = tid + TPB * j;
        if (sl < cnt) {
            float khf = cand_kv[sl];
            unsigned key = __float_as_uint(khf);
            if (key > Kstar) {
                int p = cand_idx[sl];
                out[((size_t)b * RLEN + (size_t)p) * 4 + e] = (1.f - khf) + khf;
            } else if (key == Kstar) {
                int tp = atomicAdd(&s_tcnt, 1);
                if (tp < TCAP) s_tie[tp] = cand_idx[sl];
            }
        }
    }
    __syncthreads();
    // wave 0 picks the `need` smallest tie indices (typically need==1, T==1)
    if (wid == 0) {
        int T = s_tcnt < TCAP ? s_tcnt : TCAP;
        float kv = __uint_as_float(Kstar);
        float ov = (1.f - kv) + kv;
        for (int rdone = 0; rdone < need; ++rdone) {
            int bi = 0x7fffffff, bp = -1;
            for (int i = lane; i < T; i += 64) {
                int vv = s_tie[i];
                if (vv < bi) { bi = vv; bp = i; }
            }
#pragma unroll
            for (int s2 = 32; s2; s2 >>= 1) {
                int oi = __shfl_xor(bi, s2);
                int op = __shfl_xor(bp, s2);
                if (oi < bi) { bi = oi; bp = op; }
            }
            if (lane == 0 && bi != 0x7fffffff) {
                out[((size_t)b * RLEN + (size_t)bi) * 4 + e] = ov;
                s_tie[bp] = 0x7fffffff;      // remove; wave-local LDS is ordered
            }
        }
    }
}

extern "C" void kernel_launch(void* const* d_in, const int* in_sizes, int n_in,
                              void* d_out, int out_size, void* d_ws, size_t ws_size,
                              hipStream_t stream) {
    const float* scores = (const float*)d_in[0];   // [B=64, N=256, N=256, E=4] f32
    const float* gumbel = (const float*)d_in[1];   // [B*E=256, N*N=65536] f32
    float* out = (float*)d_out;                    // [B, N, N, E] f32

    // DMA zero-fill (graph-capturable async memset), then sparse scatter.
    hipMemsetAsync(d_out, 0, (size_t)out_size * sizeof(float), stream);
    GumbelSampler_2482491097709_kernel<<<NROW, TPB, 0, stream>>>(scores, gumbel, out);
}

// Round 7
// 331.503 us; speedup vs baseline: 1.0859x; 1.0859x over previous
//
#include <hip/hip_runtime.h>
#include <cfloat>
#include <math.h>

#define NROW   256      // B*E rows
#define RLEN   65536    // N*N elements per row
#define TPB    1024
#define VPT    64       // register-resident values per thread (64*1024 = RLEN)
#define REGS   8        // candidate slots per thread
#define MAXC   (TPB*REGS)   // 8192
#define NITER  64       // scan length (local_k)
#define KSEL   64       // top-k
#define THETA_OFF 8.0f  // initial candidate threshold: M0 - 8.0
#define TCAP   256      // tie-list capacity
#define LN_TGT 7.6246f  // ln(2048): adaptive-theta target count
#define WGATE_D 1.4787e-8   // e^-18.03: suppression gate (o > this)
#define SF_EPS  1e-18f  // scaled-sum guard: below this, redo reduce in f64

// R15 = R14 (passing f64 w-space scan) minus its two counter-diagnosed costs:
// (a) SQ_LDS_BANK_CONFLICT 5k->50k in R14: f64 shfl butterfly = 2x b32 DS ops.
//     Fix: per-thread sum stays f64 (range), but the cross-lane reduce runs in
//     f32 on 2^k-scaled values (k uniform from exponent of S_prev; S_t <=
//     S_{t-1} so scaled sums are in (0,~4]). Rel err ~6e-7 << 1e-4 selection
//     margins. A UNIFORM guard (Sf < 1e-18, i.e. S dropped >e^43 in one iter,
//     ~1.5% of rows once) redoes the reduce in f64 — the R13-class tail case
//     stays exact. DS ops per wave-iter return to R12 levels.
// (b) WRITE_SIZE 24-29 MB in R12/R14: scratch spill. Pinned v[64] occupies
//     the 64 arch VGPRs; R14's f64 kh[8] (+16 regs) and 8x inlined ocml
//     exp(double) (register-hungry) overflowed the AGPR cushion to scratch.
//     Fix: kh in f32 (64 adds of <=1 values: ~4e-6 abs err, fine) and a
//     5-op w-exp: w = ldexp((double)__expf(y - n*ln2), n), n = floor(y*log2e)
//     — no ocml exp anywhere on the hot path.
// Everything else (single pinned-register global pass, adaptive theta,
// warp-aggregated collect, S<Ktrig expansion net + Rsum backfill, radix
// top-64, tie-break emit) is R14-verbatim. LDS ~83.6 KB keeps 1 block/CU.

// w = exp(10*(val - M0)) in f64 range without ocml exp(double):
// y = 10(v-M0); n = floor(y*log2e); frac = y - n*ln2 in [0, ln2);
// w = 2^n * e^frac. __expf -> v_exp_f32 (native); ldexp -> v_ldexp_f64.
// Precision ~1e-7 relative (equiv. v-perturbation 1e-8, << margins).
__device__ __forceinline__ double wexp10(float val, double M0d) {
    double y  = 10.0 * ((double)val - M0d);
    double nf = floor(y * 1.4426950408889634);
    float  fr = (float)(y - nf * 0.6931471805599453);
    return ldexp((double)__expf(fr), (int)nf);
}

__global__ void __launch_bounds__(TPB, 4)
GumbelSampler_2482491097709_kernel(const float* __restrict__ scores,
                                   const float* __restrict__ gumbel,
                                   float* __restrict__ out)
{
    __shared__ float  s_Pf[2][16];  // scan sum partials, f32-scaled (ping-pong)
    __shared__ double s_Pd[2][16];  // f64 redo partials (rare guard path)
    __shared__ float s_EA[16];      // collect/expansion max partials
    __shared__ float s_EB[16];      // collect/expansion sum partials
    __shared__ int   s_IC[16];      // adaptive-theta count partials
    __shared__ int   s_cnt;
    __shared__ int   s_selB;        // histogram: found bin (per pass)
    __shared__ int   s_selR;        // histogram: residual rank (per pass)
    __shared__ int   s_tcnt;
    __shared__ int   s_tie[TCAP];
    __shared__ int   s_hist[4096];  // 16 KB: radix passes use <=2048 bins;
                                    // oversized on purpose (LDS > 80 KB)
    __shared__ int   cand_idx[MAXC];
    __shared__ float cand_kv[MAXC]; // staging value, then final khot (f32)

    const int tid  = threadIdx.x;
    const int lane = tid & 63;
    const int wid  = tid >> 6;

    // XCD swizzle: co-locate the 4 e-blocks of each b on one XCD (perf only).
    const int q    = blockIdx.x;
    const int xcd  = q & 7;
    const int slot = q >> 3;
    const int b    = xcd * 8 + (slot & 7);
    const int e    = slot >> 3;
    const int r    = b * 4 + e;

    const float* __restrict__ sr = scores + (size_t)b * (RLEN * 4) + e;
    const float* __restrict__ gr = gumbel + (size_t)r * RLEN;

    // ---- Single global read: v[s] for positions p = tid + TPB*s; fused max ----
    float v[VPT];
    float lm = -FLT_MAX;
#pragma unroll
    for (int s = 0; s < VPT; ++s) {
        int p = tid + TPB * s;
        float x = sr[(size_t)p * 4] + gr[p];
        v[s] = x;
        lm = fmaxf(lm, x);
    }
    // Pin v[] into registers: forbids rematerialization-from-global.
#pragma unroll
    for (int s = 0; s < VPT; ++s) asm volatile("" : "+v"(v[s]));

    // ---- Block max M0 (exact; uniform via commutative fmax butterfly) ----
#pragma unroll
    for (int o = 32; o; o >>= 1) lm = fmaxf(lm, __shfl_xor(lm, o));
    if (lane == 0) s_EA[wid] = lm;
    __syncthreads();
    float M0 = s_EA[lane & 15];
#pragma unroll
    for (int o = 8; o; o >>= 1) M0 = fmaxf(M0, __shfl_xor(M0, o));
    const float  C   = M0 * 10.0f;       // f32 anchor (tail-U arithmetic)
    const double M0d = (double)M0;       // f64 anchor base for w

    // ---- Adaptive theta: exact count from registers, ln-step to ~2048 ----
    // count predicate (v[s] >= theta) is IDENTICAL to the append predicate,
    // so the final cnt equals the accepted count exactly: no overflow path.
    float theta = M0 - THETA_OFF;
    for (int probe = 0; probe < 12; ++probe) {
        int lc = 0;
#pragma unroll
        for (int s = 0; s < VPT; ++s) lc += (v[s] >= theta) ? 1 : 0;
#pragma unroll
        for (int o = 32; o; o >>= 1) lc += __shfl_xor(lc, o);
        if (lane == 0) s_IC[wid] = lc;
        __syncthreads();
        int cc = s_IC[lane & 15];
#pragma unroll
        for (int o = 8; o; o >>= 1) cc += __shfl_xor(cc, o);   // uniform
        __syncthreads();                 // s_IC reads done before next write
        if (cc > MAXC - 64)      theta += __logf((float)cc) - LN_TGT;  // up
        else if (cc < KSEL)      theta -= LN_TGT - __logf((float)(cc < 1 ? 1 : cc));
        else break;                      // 64 <= cnt <= 8128: accept
    }

    // ---- Collect candidates + frozen-tail Mu/U (from registers, f32) ----
    // Warp-aggregated append: one LDS atomic per wave-iteration.
    if (tid == 0) s_cnt = 0;
    __syncthreads();
    {
        float mu = -FLT_MAX, u = 0.f;
#pragma unroll
        for (int s = 0; s < VPT; ++s) {
            float val = v[s];
            bool pr = (val >= theta);
            unsigned long long m = __ballot(pr);
            if (pr) {
                int lead = __ffsll(m) - 1;
                int base = 0;
                if (lane == lead) base = atomicAdd(&s_cnt, (int)__popcll(m));
                base = __shfl(base, lead);
                int sl = base + (int)__popcll(m & ((1ull << lane) - 1ull));
                if (sl < MAXC) { cand_idx[sl] = tid + TPB * s; cand_kv[sl] = val; }
            } else {
                mu = fmaxf(mu, val);
                float yv = fmaf(val, 10.f, -C);
                if (yv > -87.f) u += __expf(yv);   // below -87 flushes anyway
            }
        }
#pragma unroll
        for (int o = 32; o; o >>= 1) {
            mu = fmaxf(mu, __shfl_xor(mu, o));
            u += __shfl_xor(u, o);
        }
        if (lane == 0) { s_EA[wid] = mu; s_EB[wid] = u; }
    }
    __syncthreads();                     // staging + partials visible
    int cnt = s_cnt;
    float Mu = s_EA[lane & 15], Uf = s_EB[lane & 15];
#pragma unroll
    for (int o = 8; o; o >>= 1) {
        Mu = fmaxf(Mu, __shfl_xor(Mu, o));
        Uf += __shfl_xor(Uf, o);
    }
    double Ud = (double)Uf;
    // v[] is dead past this point; the rare expansion path re-reads global
    // with identical arithmetic.

    // ---- Owner pull: w = exp(10(v-M0)) f64 via wexp10; kh = 0 (f32) ----
    double w[REGS];
    float  kh[REGS];
#pragma unroll
    for (int j = 0; j < REGS; ++j) {
        int sl = tid + TPB * j;
        if (sl < cnt) w[j] = wexp10(cand_kv[sl], M0d);
        else          w[j] = 0.0;
        kh[j] = 0.f;
    }

    // ---- f64 w-space scan, f32-scaled reduce: ONE barrier, no transcendentals ----
    // Iteration t: accumulate onehot_{t-1} (o = w*rcpS, ungated), suppress
    // w *= (1-o)^10 when o > e^-18.03, sum S_t = sum(w) + U.
    bool   noexp = false;
    double rcpS = 0.0, wT = 1e300;       // t=0: nothing suppressed
    double Rsum = 0.0;                   // sum_{tt<t} rcpS_tt (for backfill)
    double Ktrig = wexp10(Mu + 2.0f, M0d);   // = exp(10Mu - C + 20)
    int    kscale = 0;                   // uniform: 2^kscale normalizes S_prev
    for (int t = 0; t < NITER; ++t) {
        const int pb = t & 1;
        double ls = 0.0;
#pragma unroll
        for (int j = 0; j < REGS; ++j) {
            int sl = tid + TPB * j;
            if (sl < cnt) {
                double wj = w[j];
                double o  = wj * rcpS;   // onehot_{t-1} (0 at t=0)
                kh[j] += (float)o;       // ungated accumulate (f32 ok: <=64 adds of <=1)
                if (wj > wT) {           // suppression gate: o > e^-18.03
                    double m  = 1.0 - o;
                    double m2 = m * m;
                    double m4 = m2 * m2;
                    double m8 = m4 * m4;
                    wj *= m8 * m2;       // w *= (1-o)^10
                    w[j] = wj;
                }
                ls += wj;
            }
        }
        // f32-scaled cross-lane reduce (DS ops halved vs f64 shfl).
        float lsf = (float)ldexp(ls, kscale);
#pragma unroll
        for (int o = 32; o; o >>= 1) lsf += __shfl_xor(lsf, o);
        if (lane == 0) s_Pf[pb][wid] = lsf;
        __syncthreads();                 // THE one barrier of this iteration
        float Sf = s_Pf[pb][lane & 15];  // same-address bcast per 16-lane group
#pragma unroll
        for (int o = 8; o; o >>= 1) Sf += __shfl_xor(Sf, o);   // uniform
        double S;
        if (Sf >= SF_EPS) {
            S = ldexp((double)Sf, -kscale);
        } else {
            // Rare (~1.5% of rows once): S collapsed > e^43 in one iteration;
            // f32 scaling lost it. Uniform branch: redo the reduce in f64.
            double td = ls;
#pragma unroll
            for (int o = 32; o; o >>= 1) td += __shfl_xor(td, o);
            if (lane == 0) s_Pd[pb][wid] = td;
            __syncthreads();
            double Sd = s_Pd[pb][lane & 15];
#pragma unroll
            for (int o = 8; o; o >>= 1) Sd += __shfl_xor(Sd, o);
            S = Sd;
        }
        S += Ud;                         // frozen tail: direct add at anchor
        rcpS = 1.0 / S;
        wT   = S * WGATE_D;
        // kscale for next iter: 2^kscale * S in [2,4). S normal (>= ~e^-87).
        {
            int ebits = (int)((__double_as_longlong(S) >> 52) & 0x7ff);
            kscale = 1 - (ebits - 1023);
        }

        // Expansion trigger (uniform): S < Ktrig <=> 10*Mu > Lse - 20.
        if (!noexp && t < NITER - 1 && S < Ktrig) {
            double Lse  = fma(10.0, M0d, log(S));    // rare path: ocml log ok
            float thOld = theta;
            float thN   = (float)((Lse - 26.0) * 0.1);
            int   oldc  = cnt;
            float mu2 = -FLT_MAX, u2 = 0.f;
#pragma unroll 4
            for (int s = 0; s < VPT; ++s) {
                int p = tid + TPB * s;
                float val = sr[(size_t)p * 4] + gr[p];   // bit-identical v
                if (val < thOld) {
                    if (val >= thN) {
                        int sl = atomicAdd(&s_cnt, 1);
                        if (sl < MAXC) {
                            cand_idx[sl] = p;
                            cand_kv[sl]  = val;   // staged, bit-frozen
                        }
                    } else {
                        mu2 = fmaxf(mu2, val);
                        float yv = fmaf(val, 10.f, -C);
                        if (yv > -87.f) u2 += __expf(yv);
                    }
                }
            }
#pragma unroll
            for (int o = 32; o; o >>= 1) {
                mu2 = fmaxf(mu2, __shfl_xor(mu2, o));
                u2 += __shfl_xor(u2, o);
            }
            if (lane == 0) { s_EA[wid] = mu2; s_EB[wid] = u2; }
            __syncthreads();             // appends + partials visible
            int newc = s_cnt;
            if (newc > MAXC) {
                if (tid == 0) s_cnt = oldc;  // discard partial appends
                noexp = true;                // uniform; never expand again
            } else {
                float m2_ = s_EA[lane & 15], uu = s_EB[lane & 15];
#pragma unroll
                for (int o = 8; o; o >>= 1) {
                    m2_ = fmaxf(m2_, __shfl_xor(m2_, o));
                    uu += __shfl_xor(uu, o);
                }
                Mu = m2_; Ud = (double)uu; theta = thN;
                Ktrig = wexp10(Mu + 2.0f, M0d);
                // owners pull new slots: w via wexp10; khot backfill = w*Rsum
                // (= sum_{tt<t} onehot_tt, each term < e^-26).
#pragma unroll
                for (int j = 0; j < REGS; ++j) {
                    int sl = tid + TPB * j;
                    if (sl >= oldc && sl < newc) {
                        double wn = wexp10(cand_kv[sl], M0d);
                        w[j]  = wn;
                        kh[j] = (float)(wn * Rsum);
                    }
                }
                cnt = newc;
            }
        }
        Rsum += rcpS;                    // now includes rcpS_t (for t+1 joins)
    }
    // final iteration's onehot (t = NITER-1) + store khot to LDS
#pragma unroll
    for (int j = 0; j < REGS; ++j) {
        int sl = tid + TPB * j;
        if (sl < cnt) {
            cand_kv[sl] = kh[j] + (float)(w[j] * rcpS);
        }
    }
    __syncthreads();       // all khot final & visible to all threads

    // ---- Radix-histogram top-64 (exact, jax top_k tie-break) ----
    // Keys = __float_as_uint(khot), khot >= 0 -> bit order == value order.
    // kh == 0 slots are excluded (>=64 positive khot guaranteed: the true
    // top-64 each have khot >= 1.5e-5, far above fp32-zero).
    // Pass bins: [31:21] (2048), [20:10] (2048), [9:0] (1024). After each
    // pass, wave 0 finds the bin holding descending-rank Rrem and the
    // residual rank within it. After pass 3: K* = exact 64th-largest key,
    // Rrem = number of ties (== K*) to take, smallest index first.
    unsigned prefix = 0;
    int Rrem = KSEL;
    for (int pass = 0; pass < 3; ++pass) {
        const int nbins = (pass == 2) ? 1024 : 2048;
        for (int i = tid; i < nbins; i += TPB) s_hist[i] = 0;
        __syncthreads();
#pragma unroll
        for (int j = 0; j < REGS; ++j) {
            int sl = tid + TPB * j;
            if (sl < cnt) {
                unsigned key = __float_as_uint(cand_kv[sl]);
                if (key != 0u) {
                    bool m; int bin;
                    if (pass == 0)      { m = true;                     bin = key >> 21; }
                    else if (pass == 1) { m = (key >> 21) == prefix;    bin = (key >> 10) & 2047; }
                    else                { m = (key >> 10) == prefix;    bin = key & 1023; }
                    if (m) atomicAdd(&s_hist[bin], 1);
                }
            }
        }
        __syncthreads();
        if (wid == 0) {
            int Rl = Rrem, found = -1;
            const int nch = nbins >> 6;
            // pass 0: khot <= 64(1+eps) => key < bits(80.f) => bins >= 576
            // empty; skip chunks 0..22 (bins 2047..576) of the serial scan.
            const int c0 = (pass == 0) ? 23 : 0;
            for (int c = c0; c < nch && found < 0; ++c) {
                int bin = nbins - 1 - (c * 64 + lane);   // descending bins
                int h = s_hist[bin];
                int cum = h;
#pragma unroll
                for (int s2 = 1; s2 < 64; s2 <<= 1) {
                    int vv = __shfl_up(cum, s2);
                    if (lane >= s2) cum += vv;
                }
                unsigned long long mb = __ballot(cum >= Rl);
                if (mb) {
                    int fl = __ffsll(mb) - 1;            // first (highest) bin
                    int cumex = __shfl(cum, fl) - __shfl(h, fl);
                    found = nbins - 1 - (c * 64 + fl);
                    Rl -= cumex;                          // rank inside bin
                } else {
                    Rl -= __shfl(cum, 63);                // whole chunk above
                }
            }
            if (lane == 0) { s_selB = found; s_selR = Rl; }
        }
        __syncthreads();
        prefix = (prefix << ((pass == 2) ? 10 : 11)) | (unsigned)s_selB;
        Rrem = s_selR;
    }
    const unsigned Kstar = prefix;       // exact 64th-largest key
    const int need = Rrem;               // ties to take (>= 1)

    // ---- Emit: all key > K*; collect ties == K* ----
    if (tid == 0) s_tcnt = 0;
    __syncthreads();
#pragma unroll
    for (int j = 0; j < REGS; ++j) {
        int sl = tid + TPB * j;
        if (sl < cnt) {
            float khf = cand_kv[sl];
            unsigned key = __float_as_uint(khf);
            if (key > Kstar) {
                int p = cand_idx[sl];
                out[((size_t)b * RLEN + (size_t)p) * 4 + e] = (1.f - khf) + khf;
            } else if (key == Kstar) {
                int tp = atomicAdd(&s_tcnt, 1);
                if (tp < TCAP) s_tie[tp] = cand_idx[sl];
            }
        }
    }
    __syncthreads();
    // wave 0 picks the `need` smallest tie indices (typically need==1, T==1)
    if (wid == 0) {
        int T = s_tcnt < TCAP ? s_tcnt : TCAP;
        float kv = __uint_as_float(Kstar);
        float ov = (1.f - kv) + kv;
        for (int rdone = 0; rdone < need; ++rdone) {
            int bi = 0x7fffffff, bp = -1;
            for (int i = lane; i < T; i += 64) {
                int vv = s_tie[i];
                if (vv < bi) { bi = vv; bp = i; }
            }
#pragma unroll
            for (int s2 = 32; s2; s2 >>= 1) {
                int oi = __shfl_xor(bi, s2);
                int op = __shfl_xor(bp, s2);
                if (oi < bi) { bi = oi; bp = op; }
            }
            if (lane == 0 && bi != 0x7fffffff) {
                out[((size_t)b * RLEN + (size_t)bi) * 4 + e] = ov;
                s_tie[bp] = 0x7fffffff;      // remove; wave-local LDS is ordered
            }
        }
    }
}

extern "C" void kernel_launch(void* const* d_in, const int* in_sizes, int n_in,
                              void* d_out, int out_size, void* d_ws, size_t ws_size,
                              hipStream_t stream) {
    const float* scores = (const float*)d_in[0];   // [B=64, N=256, N=256, E=4] f32
    const float* gumbel = (const float*)d_in[1];   // [B*E=256, N*N=65536] f32
    float* out = (float*)d_out;                    // [B, N, N, E] f32

    // DMA zero-fill (graph-capturable async memset), then sparse scatter.
    hipMemsetAsync(d_out, 0, (size_t)out_size * sizeof(float), stream);
    GumbelSampler_2482491097709_kernel<<<NROW, TPB, 0, stream>>>(scores, gumbel, out);
}

// Round 8
// 330.088 us; speedup vs baseline: 1.0906x; 1.0043x over previous
//
#include <hip/hip_runtime.h>
#include <cfloat>
#include <math.h>

#define NROW   256      // B*E rows
#define RLEN   65536    // N*N elements per row
#define TPB    1024
#define VPT    64       // register-resident values per thread (64*1024 = RLEN)
#define REGS   8        // candidate slots per thread
#define MAXC   (TPB*REGS)   // 8192
#define NITER  64       // scan length (local_k)
#define KSEL   64       // top-k
#define THETA_OFF 8.0f  // initial candidate threshold: M0 - 8.0
#define TCAP   256      // tie-list capacity
#define LN_TGT 7.6246f  // ln(2048): adaptive-theta target count
#define WGATE_D 1.4787e-8   // e^-18.03: suppression gate (o > this)
#define SF_EPS  1e-18f  // scaled-sum guard: below this, redo reduce in f64

// R16 = R15 + ONE change: __attribute__((amdgpu_waves_per_eu(4,4))).
// DIAGNOSIS (R10..R15 counter history): VGPR_Count has been pinned at 64
// in EVERY round — __launch_bounds__' 2nd arg is only a MINIMUM waves/EU;
// the allocator still TARGETS 8 waves/EU (64-reg budget) and reaches it by
// spilling everything beyond the pinned v[64] to scratch. f64 scan state
// (w[8], kh[8]) cannot live in AGPRs (f64 VALU reads arch VGPRs only; AGPRs
// are MFMA-only on the compute path) -> reloaded from scratch in each of
// the 64 scan iterations: WRITE_SIZE 23-29 MB, VALUBusy 31%->19%, dur up.
// The occupancy the compiler buys with 64 regs is unobtainable anyway:
// LDS 84 KB caps residency at 1 block/CU = 16 waves = exactly 4 waves/EU.
// waves_per_eu(4,4) pins the budget to 128 regs/thread: v[64] + w[8](16)
// + kh[8](8) + f64 scalars(8) + temps ~= 124 <= 128 -> zero spill expected.
// Everything else (f32-scaled reduce + f64 guard, wexp10, single pinned
// global pass, adaptive theta, warp-aggregated collect, S<Ktrig expansion
// net + Rsum backfill, radix top-64, tie-break emit) is R15-verbatim
// (passed, absmax 0.0). LDS ~83.6 KB keeps 1 block/CU.

// w = exp(10*(val - M0)) in f64 range without ocml exp(double):
// y = 10(v-M0); n = floor(y*log2e); frac = y - n*ln2 in [0, ln2);
// w = 2^n * e^frac. __expf -> v_exp_f32 (native); ldexp -> v_ldexp_f64.
// Precision ~1e-7 relative (equiv. v-perturbation 1e-8, << margins).
__device__ __forceinline__ double wexp10(float val, double M0d) {
    double y  = 10.0 * ((double)val - M0d);
    double nf = floor(y * 1.4426950408889634);
    float  fr = (float)(y - nf * 0.6931471805599453);
    return ldexp((double)__expf(fr), (int)nf);
}

__global__ void __launch_bounds__(TPB)
__attribute__((amdgpu_waves_per_eu(4, 4)))
GumbelSampler_2482491097709_kernel(const float* __restrict__ scores,
                                   const float* __restrict__ gumbel,
                                   float* __restrict__ out)
{
    __shared__ float  s_Pf[2][16];  // scan sum partials, f32-scaled (ping-pong)
    __shared__ double s_Pd[2][16];  // f64 redo partials (rare guard path)
    __shared__ float s_EA[16];      // collect/expansion max partials
    __shared__ float s_EB[16];      // collect/expansion sum partials
    __shared__ int   s_IC[16];      // adaptive-theta count partials
    __shared__ int   s_cnt;
    __shared__ int   s_selB;        // histogram: found bin (per pass)
    __shared__ int   s_selR;        // histogram: residual rank (per pass)
    __shared__ int   s_tcnt;
    __shared__ int   s_tie[TCAP];
    __shared__ int   s_hist[4096];  // 16 KB: radix passes use <=2048 bins;
                                    // oversized on purpose (LDS > 80 KB)
    __shared__ int   cand_idx[MAXC];
    __shared__ float cand_kv[MAXC]; // staging value, then final khot (f32)

    const int tid  = threadIdx.x;
    const int lane = tid & 63;
    const int wid  = tid >> 6;

    // XCD swizzle: co-locate the 4 e-blocks of each b on one XCD (perf only).
    const int q    = blockIdx.x;
    const int xcd  = q & 7;
    const int slot = q >> 3;
    const int b    = xcd * 8 + (slot & 7);
    const int e    = slot >> 3;
    const int r    = b * 4 + e;

    const float* __restrict__ sr = scores + (size_t)b * (RLEN * 4) + e;
    const float* __restrict__ gr = gumbel + (size_t)r * RLEN;

    // ---- Single global read: v[s] for positions p = tid + TPB*s; fused max ----
    float v[VPT];
    float lm = -FLT_MAX;
#pragma unroll
    for (int s = 0; s < VPT; ++s) {
        int p = tid + TPB * s;
        float x = sr[(size_t)p * 4] + gr[p];
        v[s] = x;
        lm = fmaxf(lm, x);
    }
    // Pin v[] into registers: forbids rematerialization-from-global.
#pragma unroll
    for (int s = 0; s < VPT; ++s) asm volatile("" : "+v"(v[s]));

    // ---- Block max M0 (exact; uniform via commutative fmax butterfly) ----
#pragma unroll
    for (int o = 32; o; o >>= 1) lm = fmaxf(lm, __shfl_xor(lm, o));
    if (lane == 0) s_EA[wid] = lm;
    __syncthreads();
    float M0 = s_EA[lane & 15];
#pragma unroll
    for (int o = 8; o; o >>= 1) M0 = fmaxf(M0, __shfl_xor(M0, o));
    const float  C   = M0 * 10.0f;       // f32 anchor (tail-U arithmetic)
    const double M0d = (double)M0;       // f64 anchor base for w

    // ---- Adaptive theta: exact count from registers, ln-step to ~2048 ----
    // count predicate (v[s] >= theta) is IDENTICAL to the append predicate,
    // so the final cnt equals the accepted count exactly: no overflow path.
    float theta = M0 - THETA_OFF;
    for (int probe = 0; probe < 12; ++probe) {
        int lc = 0;
#pragma unroll
        for (int s = 0; s < VPT; ++s) lc += (v[s] >= theta) ? 1 : 0;
#pragma unroll
        for (int o = 32; o; o >>= 1) lc += __shfl_xor(lc, o);
        if (lane == 0) s_IC[wid] = lc;
        __syncthreads();
        int cc = s_IC[lane & 15];
#pragma unroll
        for (int o = 8; o; o >>= 1) cc += __shfl_xor(cc, o);   // uniform
        __syncthreads();                 // s_IC reads done before next write
        if (cc > MAXC - 64)      theta += __logf((float)cc) - LN_TGT;  // up
        else if (cc < KSEL)      theta -= LN_TGT - __logf((float)(cc < 1 ? 1 : cc));
        else break;                      // 64 <= cnt <= 8128: accept
    }

    // ---- Collect candidates + frozen-tail Mu/U (from registers, f32) ----
    // Warp-aggregated append: one LDS atomic per wave-iteration.
    if (tid == 0) s_cnt = 0;
    __syncthreads();
    {
        float mu = -FLT_MAX, u = 0.f;
#pragma unroll
        for (int s = 0; s < VPT; ++s) {
            float val = v[s];
            bool pr = (val >= theta);
            unsigned long long m = __ballot(pr);
            if (pr) {
                int lead = __ffsll(m) - 1;
                int base = 0;
                if (lane == lead) base = atomicAdd(&s_cnt, (int)__popcll(m));
                base = __shfl(base, lead);
                int sl = base + (int)__popcll(m & ((1ull << lane) - 1ull));
                if (sl < MAXC) { cand_idx[sl] = tid + TPB * s; cand_kv[sl] = val; }
            } else {
                mu = fmaxf(mu, val);
                float yv = fmaf(val, 10.f, -C);
                if (yv > -87.f) u += __expf(yv);   // below -87 flushes anyway
            }
        }
#pragma unroll
        for (int o = 32; o; o >>= 1) {
            mu = fmaxf(mu, __shfl_xor(mu, o));
            u += __shfl_xor(u, o);
        }
        if (lane == 0) { s_EA[wid] = mu; s_EB[wid] = u; }
    }
    __syncthreads();                     // staging + partials visible
    int cnt = s_cnt;
    float Mu = s_EA[lane & 15], Uf = s_EB[lane & 15];
#pragma unroll
    for (int o = 8; o; o >>= 1) {
        Mu = fmaxf(Mu, __shfl_xor(Mu, o));
        Uf += __shfl_xor(Uf, o);
    }
    double Ud = (double)Uf;
    // v[] is dead past this point; the rare expansion path re-reads global
    // with identical arithmetic.

    // ---- Owner pull: w = exp(10(v-M0)) f64 via wexp10; kh = 0 (f32) ----
    double w[REGS];
    float  kh[REGS];
#pragma unroll
    for (int j = 0; j < REGS; ++j) {
        int sl = tid + TPB * j;
        if (sl < cnt) w[j] = wexp10(cand_kv[sl], M0d);
        else          w[j] = 0.0;
        kh[j] = 0.f;
    }

    // ---- f64 w-space scan, f32-scaled reduce: ONE barrier, no transcendentals ----
    // Iteration t: accumulate onehot_{t-1} (o = w*rcpS, ungated), suppress
    // w *= (1-o)^10 when o > e^-18.03, sum S_t = sum(w) + U.
    bool   noexp = false;
    double rcpS = 0.0, wT = 1e300;       // t=0: nothing suppressed
    double Rsum = 0.0;                   // sum_{tt<t} rcpS_tt (for backfill)
    double Ktrig = wexp10(Mu + 2.0f, M0d);   // = exp(10Mu - C + 20)
    int    kscale = 0;                   // uniform: 2^kscale normalizes S_prev
    for (int t = 0; t < NITER; ++t) {
        const int pb = t & 1;
        double ls = 0.0;
#pragma unroll
        for (int j = 0; j < REGS; ++j) {
            int sl = tid + TPB * j;
            if (sl < cnt) {
                double wj = w[j];
                double o  = wj * rcpS;   // onehot_{t-1} (0 at t=0)
                kh[j] += (float)o;       // ungated accumulate (f32 ok: <=64 adds of <=1)
                if (wj > wT) {           // suppression gate: o > e^-18.03
                    double m  = 1.0 - o;
                    double m2 = m * m;
                    double m4 = m2 * m2;
                    double m8 = m4 * m4;
                    wj *= m8 * m2;       // w *= (1-o)^10
                    w[j] = wj;
                }
                ls += wj;
            }
        }
        // f32-scaled cross-lane reduce (DS ops halved vs f64 shfl).
        float lsf = (float)ldexp(ls, kscale);
#pragma unroll
        for (int o = 32; o; o >>= 1) lsf += __shfl_xor(lsf, o);
        if (lane == 0) s_Pf[pb][wid] = lsf;
        __syncthreads();                 // THE one barrier of this iteration
        float Sf = s_Pf[pb][lane & 15];  // same-address bcast per 16-lane group
#pragma unroll
        for (int o = 8; o; o >>= 1) Sf += __shfl_xor(Sf, o);   // uniform
        double S;
        if (Sf >= SF_EPS) {
            S = ldexp((double)Sf, -kscale);
        } else {
            // Rare (~1.5% of rows once): S collapsed > e^43 in one iteration;
            // f32 scaling lost it. Uniform branch: redo the reduce in f64.
            double td = ls;
#pragma unroll
            for (int o = 32; o; o >>= 1) td += __shfl_xor(td, o);
            if (lane == 0) s_Pd[pb][wid] = td;
            __syncthreads();
            double Sd = s_Pd[pb][lane & 15];
#pragma unroll
            for (int o = 8; o; o >>= 1) Sd += __shfl_xor(Sd, o);
            S = Sd;
        }
        S += Ud;                         // frozen tail: direct add at anchor
        rcpS = 1.0 / S;
        wT   = S * WGATE_D;
        // kscale for next iter: 2^kscale * S in [2,4). S normal (>= ~e^-87).
        {
            int ebits = (int)((__double_as_longlong(S) >> 52) & 0x7ff);
            kscale = 1 - (ebits - 1023);
        }

        // Expansion trigger (uniform): S < Ktrig <=> 10*Mu > Lse - 20.
        if (!noexp && t < NITER - 1 && S < Ktrig) {
            double Lse  = fma(10.0, M0d, log(S));    // rare path: ocml log ok
            float thOld = theta;
            float thN   = (float)((Lse - 26.0) * 0.1);
            int   oldc  = cnt;
            float mu2 = -FLT_MAX, u2 = 0.f;
#pragma unroll 4
            for (int s = 0; s < VPT; ++s) {
                int p = tid + TPB * s;
                float val = sr[(size_t)p * 4] + gr[p];   // bit-identical v
                if (val < thOld) {
                    if (val >= thN) {
                        int sl = atomicAdd(&s_cnt, 1);
                        if (sl < MAXC) {
                            cand_idx[sl] = p;
                            cand_kv[sl]  = val;   // staged, bit-frozen
                        }
                    } else {
                        mu2 = fmaxf(mu2, val);
                        float yv = fmaf(val, 10.f, -C);
                        if (yv > -87.f) u2 += __expf(yv);
                    }
                }
            }
#pragma unroll
            for (int o = 32; o; o >>= 1) {
                mu2 = fmaxf(mu2, __shfl_xor(mu2, o));
                u2 += __shfl_xor(u2, o);
            }
            if (lane == 0) { s_EA[wid] = mu2; s_EB[wid] = u2; }
            __syncthreads();             // appends + partials visible
            int newc = s_cnt;
            if (newc > MAXC) {
                if (tid == 0) s_cnt = oldc;  // discard partial appends
                noexp = true;                // uniform; never expand again
            } else {
                float m2_ = s_EA[lane & 15], uu = s_EB[lane & 15];
#pragma unroll
                for (int o = 8; o; o >>= 1) {
                    m2_ = fmaxf(m2_, __shfl_xor(m2_, o));
                    uu += __shfl_xor(uu, o);
                }
                Mu = m2_; Ud = (double)uu; theta = thN;
                Ktrig = wexp10(Mu + 2.0f, M0d);
                // owners pull new slots: w via wexp10; khot backfill = w*Rsum
                // (= sum_{tt<t} onehot_tt, each term < e^-26).
#pragma unroll
                for (int j = 0; j < REGS; ++j) {
                    int sl = tid + TPB * j;
                    if (sl >= oldc && sl < newc) {
                        double wn = wexp10(cand_kv[sl], M0d);
                        w[j]  = wn;
                        kh[j] = (float)(wn * Rsum);
                    }
                }
                cnt = newc;
            }
        }
        Rsum += rcpS;                    // now includes rcpS_t (for t+1 joins)
    }
    // final iteration's onehot (t = NITER-1) + store khot to LDS
#pragma unroll
    for (int j = 0; j < REGS; ++j) {
        int sl = tid + TPB * j;
        if (sl < cnt) {
            cand_kv[sl] = kh[j] + (float)(w[j] * rcpS);
        }
    }
    __syncthreads();       // all khot final & visible to all threads

    // ---- Radix-histogram top-64 (exact, jax top_k tie-break) ----
    // Keys = __float_as_uint(khot), khot >= 0 -> bit order == value order.
    // kh == 0 slots are excluded (>=64 positive khot guaranteed: the true
    // top-64 each have khot >= 1.5e-5, far above fp32-zero).
    // Pass bins: [31:21] (2048), [20:10] (2048), [9:0] (1024). After each
    // pass, wave 0 finds the bin holding descending-rank Rrem and the
    // residual rank within it. After pass 3: K* = exact 64th-largest key,
    // Rrem = number of ties (== K*) to take, smallest index first.
    unsigned prefix = 0;
    int Rrem = KSEL;
    for (int pass = 0; pass < 3; ++pass) {
        const int nbins = (pass == 2) ? 1024 : 2048;
        for (int i = tid; i < nbins; i += TPB) s_hist[i] = 0;
        __syncthreads();
#pragma unroll
        for (int j = 0; j < REGS; ++j) {
            int sl = tid + TPB * j;
            if (sl < cnt) {
                unsigned key = __float_as_uint(cand_kv[sl]);
                if (key != 0u) {
                    bool m; int bin;
                    if (pass == 0)      { m = true;                     bin = key >> 21; }
                    else if (pass == 1) { m = (key >> 21) == prefix;    bin = (key >> 10) & 2047; }
                    else                { m = (key >> 10) == prefix;    bin = key & 1023; }
                    if (m) atomicAdd(&s_hist[bin], 1);
                }
            }
        }
        __syncthreads();
        if (wid == 0) {
            int Rl = Rrem, found = -1;
            const int nch = nbins >> 6;
            // pass 0: khot <= 64(1+eps) => key < bits(80.f) => bins >= 576
            // empty; skip chunks 0..22 (bins 2047..576) of the serial scan.
            const int c0 = (pass == 0) ? 23 : 0;
            for (int c = c0; c < nch && found < 0; ++c) {
                int bin = nbins - 1 - (c * 64 + lane);   // descending bins
                int h = s_hist[bin];
                int cum = h;
#pragma unroll
                for (int s2 = 1; s2 < 64; s2 <<= 1) {
                    int vv = __shfl_up(cum, s2);
                    if (lane >= s2) cum += vv;
                }
                unsigned long long mb = __ballot(cum >= Rl);
                if (mb) {
                    int fl = __ffsll(mb) - 1;            // first (highest) bin
                    int cumex = __shfl(cum, fl) - __shfl(h, fl);
                    found = nbins - 1 - (c * 64 + fl);
                    Rl -= cumex;                          // rank inside bin
                } else {
                    Rl -= __shfl(cum, 63);                // whole chunk above
                }
            }
            if (lane == 0) { s_selB = found; s_selR = Rl; }
        }
        __syncthreads();
        prefix = (prefix << ((pass == 2) ? 10 : 11)) | (unsigned)s_selB;
        Rrem = s_selR;
    }
    const unsigned Kstar = prefix;       // exact 64th-largest key
    const int need = Rrem;               // ties to take (>= 1)

    // ---- Emit: all key > K*; collect ties == K* ----
    if (tid == 0) s_tcnt = 0;
    __syncthreads();
#pragma unroll
    for (int j = 0; j < REGS; ++j) {
        int sl = tid + TPB * j;
        if (sl < cnt) {
            float khf = cand_kv[sl];
            unsigned key = __float_as_uint(khf);
            if (key > Kstar) {
                int p = cand_idx[sl];
                out[((size_t)b * RLEN + (size_t)p) * 4 + e] = (1.f - khf) + khf;
            } else if (key == Kstar) {
                int tp = atomicAdd(&s_tcnt, 1);
                if (tp < TCAP) s_tie[tp] = cand_idx[sl];
            }
        }
    }
    __syncthreads();
    // wave 0 picks the `need` smallest tie indices (typically need==1, T==1)
    if (wid == 0) {
        int T = s_tcnt < TCAP ? s_tcnt : TCAP;
        float kv = __uint_as_float(Kstar);
        float ov = (1.f - kv) + kv;
        for (int rdone = 0; rdone < need; ++rdone) {
            int bi = 0x7fffffff, bp = -1;
            for (int i = lane; i < T; i += 64) {
                int vv = s_tie[i];
                if (vv < bi) { bi = vv; bp = i; }
            }
#pragma unroll
            for (int s2 = 32; s2; s2 >>= 1) {
                int oi = __shfl_xor(bi, s2);
                int op = __shfl_xor(bp, s2);
                if (oi < bi) { bi = oi; bp = op; }
            }
            if (lane == 0 && bi != 0x7fffffff) {
                out[((size_t)b * RLEN + (size_t)bi) * 4 + e] = ov;
                s_tie[bp] = 0x7fffffff;      // remove; wave-local LDS is ordered
            }
        }
    }
}

extern "C" void kernel_launch(void* const* d_in, const int* in_sizes, int n_in,
                              void* d_out, int out_size, void* d_ws, size_t ws_size,
                              hipStream_t stream) {
    const float* scores = (const float*)d_in[0];   // [B=64, N=256, N=256, E=4] f32
    const float* gumbel = (const float*)d_in[1];   // [B*E=256, N*N=65536] f32
    float* out = (float*)d_out;                    // [B, N, N, E] f32

    // DMA zero-fill (graph-capturable async memset), then sparse scatter.
    hipMemsetAsync(d_out, 0, (size_t)out_size * sizeof(float), stream);
    GumbelSampler_2482491097709_kernel<<<NROW, TPB, 0, stream>>>(scores, gumbel, out);
}